// Round 6
// baseline (602.598 us; speedup 1.0000x reference)
//
#include <hip/hip_runtime.h>
#include <hip/hip_bf16.h>

// Problem constants: T=1024, B=8, D=1024, N_HEAD=16, D_HEAD=64
// I/O dtype: fp32 (per reference). Internal compute: bf16 MFMA with fp32 accum.
// heads buffer layout: [T*B][3072] bf16, cols [0,1024)=Q, [1024,2048)=K, [2048,3072)=V

typedef __bf16 v8bf __attribute__((ext_vector_type(8)));
typedef float  v4f  __attribute__((ext_vector_type(4)));
typedef unsigned short v8us __attribute__((ext_vector_type(8)));

#define MFMA16x16x32(a, b, c) __builtin_amdgcn_mfma_f32_16x16x32_bf16(a, b, c, 0, 0, 0)

__device__ __forceinline__ unsigned short f2bf(float f) {
    unsigned int u = __float_as_uint(f);
    u = (u + 0x7FFF + ((u >> 16) & 1)) >> 16;   // RNE
    return (unsigned short)u;
}

// ---------------- prep: x_bf16 = bf16(input_f32 + pos_enc_f32) ----------------
__global__ __launch_bounds__(256) void prep_x(const float* __restrict__ in,
                                              const float* __restrict__ pe,
                                              unsigned short* __restrict__ x) {
    size_t idx = ((size_t)blockIdx.x * 256 + threadIdx.x) * 8;
    v4f a0 = *(const v4f*)(in + idx);
    v4f a1 = *(const v4f*)(in + idx + 4);
    v4f p0 = *(const v4f*)(pe + idx);
    v4f p1 = *(const v4f*)(pe + idx + 4);
    v8us r;
    unsigned short* rp = (unsigned short*)&r;
#pragma unroll
    for (int q = 0; q < 4; q++) {
        rp[q]     = f2bf(a0[q] + p0[q]);
        rp[q + 4] = f2bf(a1[q] + p1[q]);
    }
    *(v8us*)(x + idx) = r;
}

// -------- tiled transpose + cast: src_f32[R][C] -> dst_bf16[C][R] ----------
__global__ __launch_bounds__(256) void transpose_f32_bf16(const float* __restrict__ src,
                                                          unsigned short* __restrict__ dst,
                                                          int R, int C) {
    __shared__ alignas(16) unsigned short t[64][72];
    int c0 = blockIdx.x * 64, r0 = blockIdx.y * 64;
    int tid = threadIdx.x;
    int rr = tid >> 2, cg = (tid & 3) * 16;
    const float* s = src + (size_t)(r0 + rr) * C + c0 + cg;
#pragma unroll
    for (int q4 = 0; q4 < 4; q4++) {
        v4f v = *(const v4f*)(s + q4 * 4);
#pragma unroll
        for (int q = 0; q < 4; q++) t[rr][cg + q4 * 4 + q] = f2bf(v[q]);
    }
    __syncthreads();
    v8us o0, o1;
    unsigned short* o0p = (unsigned short*)&o0;
    unsigned short* o1p = (unsigned short*)&o1;
#pragma unroll
    for (int q = 0; q < 8; q++) {
        o0p[q] = t[cg + q][rr];
        o1p[q] = t[cg + 8 + q][rr];
    }
    *(v8us*)(dst + (size_t)(c0 + rr) * R + r0 + cg)     = o0;
    *(v8us*)(dst + (size_t)(c0 + rr) * R + r0 + cg + 8) = o1;
}

// ---------------- GEMM: C[M][N] = A[M][K] * Bt[N][K]^T, bf16 in, fp32 acc --------
template <bool F32OUT>
__global__ __launch_bounds__(256) void gemm_bf16(const unsigned short* __restrict__ A,
                                                 const unsigned short* __restrict__ Bt,
                                                 void* __restrict__ Cout,
                                                 int M, int N, int K) {
    __shared__ alignas(16) unsigned short As[128][40];
    __shared__ alignas(16) unsigned short Bs[128][40];
    const int tid = threadIdx.x;
    const int lane = tid & 63, wave = tid >> 6;
    const int quad = lane >> 4, lq = lane & 15;
    const int m0 = blockIdx.y * 128, n0 = blockIdx.x * 128;
    const int mW = (wave & 1) * 64, nW = (wave >> 1) * 64;

    v4f acc[4][4];
#pragma unroll
    for (int mi = 0; mi < 4; mi++)
#pragma unroll
        for (int ni = 0; ni < 4; ni++) acc[mi][ni] = (v4f){0.f, 0.f, 0.f, 0.f};

    const int srow = tid >> 1, shalf = (tid & 1) * 16;
    const unsigned short* ag = A  + (size_t)(m0 + srow) * K + shalf;
    const unsigned short* bg = Bt + (size_t)(n0 + srow) * K + shalf;

    for (int k0 = 0; k0 < K; k0 += 32) {
        v8us a0 = *(const v8us*)(ag + k0);
        v8us a1 = *(const v8us*)(ag + k0 + 8);
        v8us b0 = *(const v8us*)(bg + k0);
        v8us b1 = *(const v8us*)(bg + k0 + 8);
        __syncthreads();
        *(v8us*)&As[srow][shalf]     = a0;
        *(v8us*)&As[srow][shalf + 8] = a1;
        *(v8us*)&Bs[srow][shalf]     = b0;
        *(v8us*)&Bs[srow][shalf + 8] = b1;
        __syncthreads();
        v8bf af[4], bfr[4];
#pragma unroll
        for (int mi = 0; mi < 4; mi++) af[mi]  = *(const v8bf*)&As[mW + mi * 16 + lq][quad * 8];
#pragma unroll
        for (int ni = 0; ni < 4; ni++) bfr[ni] = *(const v8bf*)&Bs[nW + ni * 16 + lq][quad * 8];
#pragma unroll
        for (int mi = 0; mi < 4; mi++)
#pragma unroll
            for (int ni = 0; ni < 4; ni++)
                acc[mi][ni] = MFMA16x16x32(af[mi], bfr[ni], acc[mi][ni]);
    }

#pragma unroll
    for (int mi = 0; mi < 4; mi++)
#pragma unroll
        for (int ni = 0; ni < 4; ni++)
#pragma unroll
            for (int r = 0; r < 4; r++) {
                int row = m0 + mW + mi * 16 + quad * 4 + r;
                int col = n0 + nW + ni * 16 + lq;
                if (F32OUT)
                    ((float*)Cout)[(size_t)row * N + col] = acc[mi][ni][r];
                else
                    ((unsigned short*)Cout)[(size_t)row * N + col] = f2bf(acc[mi][ni][r]);
            }
}

// ---------------- attention constants ----------------
#define AT_T  1024
#define AT_B  8
#define AT_NH 16
#define AT_HS 3072
#define AT_ALPHA 0.18033688011112042f  // (1/8) * log2(e)

// ------- transpose V: heads V-cols -> vt[b][n][d][j] (bf16), per-(b,n) 64x64 tiles ---
__global__ __launch_bounds__(256) void transpose_v(const unsigned short* __restrict__ heads,
                                                   unsigned short* __restrict__ vt) {
    __shared__ alignas(16) unsigned short t[64][72];
    const int j0 = blockIdx.x * 64, n = blockIdx.y, b = blockIdx.z;
    const int tid = threadIdx.x;
    const int jr = tid >> 2, dg = (tid & 3) * 16;
    size_t src = ((size_t)(j0 + jr) * 8 + b) * AT_HS + 2048 + n * 64 + dg;
    *(v8us*)&t[jr][dg]     = *(const v8us*)(heads + src);
    *(v8us*)&t[jr][dg + 8] = *(const v8us*)(heads + src + 8);
    __syncthreads();
    const int dd = tid >> 2, jg = (tid & 3) * 16;
    v8us o0, o1;
    unsigned short* o0p = (unsigned short*)&o0;
    unsigned short* o1p = (unsigned short*)&o1;
#pragma unroll
    for (int q = 0; q < 8; q++) {
        o0p[q] = t[jg + q][dd];
        o1p[q] = t[jg + 8 + q][dd];
    }
    size_t dst = ((size_t)(b * 16 + n) * 64 + dd) * 1024 + j0 + jg;
    *(v8us*)(vt + dst)     = o0;
    *(v8us*)(vt + dst + 8) = o1;
}

// ---------------- attn_fused2: single-pass online-softmax flash attention ----------------
// Block = (i-tile, bn-group-of-4); wave w handles head bn = bg*4+w for the same 16 i-rows
// (identical causal trip count per wave). K B-frags direct from global (vectorized);
// V B-frags from pre-transposed vt (vectorized); P via per-wave LDS tile.
__global__ __launch_bounds__(256) void attn_fused2(const unsigned short* __restrict__ heads,
                                                   const unsigned short* __restrict__ vt,
                                                   unsigned short* __restrict__ av,
                                                   float* __restrict__ mBuf,
                                                   float* __restrict__ lBuf) {
    __shared__ alignas(16) unsigned short Ps[4][16][40];
    const int i0 = blockIdx.x * 16;
    const int tid = threadIdx.x, wave = tid >> 6, lane = tid & 63;
    const int quad = lane >> 4, lq = lane & 15;
    const int bn = blockIdx.y * 4 + wave;
    const int b = bn >> 4, n = bn & 15;

    size_t qbase = ((size_t)(i0 + lq) * 8 + b) * AT_HS + n * 64 + quad * 8;
    v8bf q0 = *(const v8bf*)(heads + qbase);
    v8bf q1 = *(const v8bf*)(heads + qbase + 32);
    const unsigned short* vb = vt + (size_t)bn * 64 * 1024;

    float M[4], Sl[4];
    v4f o[4];
#pragma unroll
    for (int r = 0; r < 4; r++) { M[r] = -1e30f; Sl[r] = 0.f; }
#pragma unroll
    for (int dt = 0; dt < 4; dt++) o[dt] = (v4f){0.f, 0.f, 0.f, 0.f};

    for (int j0 = 0; j0 <= i0; j0 += 32) {
        // scores for 2 j-tiles
        v4f s0 = (v4f){0.f, 0.f, 0.f, 0.f}, s1 = s0;
        {
            size_t kb0 = ((size_t)(j0 + lq) * 8 + b) * AT_HS + 1024 + n * 64 + quad * 8;
            size_t kb1 = ((size_t)(j0 + 16 + lq) * 8 + b) * AT_HS + 1024 + n * 64 + quad * 8;
            v8bf ka = *(const v8bf*)(heads + kb0);
            v8bf kb = *(const v8bf*)(heads + kb0 + 32);
            v8bf kc = *(const v8bf*)(heads + kb1);
            v8bf kd = *(const v8bf*)(heads + kb1 + 32);
            s0 = MFMA16x16x32(q0, ka, s0);
            s0 = MFMA16x16x32(q1, kb, s0);
            s1 = MFMA16x16x32(q0, kc, s1);
            s1 = MFMA16x16x32(q1, kd, s1);
        }
        int ja = j0 + lq, jb_ = j0 + 16 + lq;
        float v0[4], v1[4], cm[4];
#pragma unroll
        for (int r = 0; r < 4; r++) {
            int i = i0 + quad * 4 + r;
            v0[r] = (ja  <= i) ? s0[r] * AT_ALPHA : -1e30f;
            v1[r] = (jb_ <= i) ? s1[r] * AT_ALPHA : -1e30f;
            cm[r] = fmaxf(v0[r], v1[r]);
        }
#pragma unroll
        for (int mask = 1; mask < 16; mask <<= 1)
#pragma unroll
            for (int r = 0; r < 4; r++)
                cm[r] = fmaxf(cm[r], __shfl_xor(cm[r], mask));
#pragma unroll
        for (int r = 0; r < 4; r++) {
            float Mn = fmaxf(M[r], cm[r]);
            float alpha = exp2f(M[r] - Mn);
            M[r] = Mn;
            float p0 = exp2f(v0[r] - Mn);   // masked: exp2(-1e30 - Mn) = 0
            float p1 = exp2f(v1[r] - Mn);
            Sl[r] = Sl[r] * alpha + p0 + p1;
#pragma unroll
            for (int dt = 0; dt < 4; dt++) o[dt][r] *= alpha;
            Ps[wave][quad * 4 + r][lq]      = f2bf(p0);
            Ps[wave][quad * 4 + r][16 + lq] = f2bf(p1);
        }
        __syncthreads();   // same trip count across waves; orders LDS write->read
        v8bf pf = *(const v8bf*)&Ps[wave][lq][quad * 8];
#pragma unroll
        for (int dt = 0; dt < 4; dt++) {
            v8bf vf = *(const v8bf*)(vb + (size_t)(dt * 16 + lq) * 1024 + j0 + quad * 8);
            o[dt] = MFMA16x16x32(pf, vf, o[dt]);
        }
        __syncthreads();   // Ps reused next chunk
    }

    // reduce per-lane partial sums across the 16 lanes of each row
#pragma unroll
    for (int mask = 1; mask < 16; mask <<= 1)
#pragma unroll
        for (int r = 0; r < 4; r++)
            Sl[r] += __shfl_xor(Sl[r], mask);
    float linv[4];
#pragma unroll
    for (int r = 0; r < 4; r++) linv[r] = __builtin_amdgcn_rcpf(Sl[r]);
    if (lq == 0) {
#pragma unroll
        for (int r = 0; r < 4; r++) {
            int i = i0 + quad * 4 + r;
            mBuf[(size_t)bn * AT_T + i] = M[r];
            lBuf[(size_t)bn * AT_T + i] = Sl[r];
        }
    }
#pragma unroll
    for (int dt = 0; dt < 4; dt++)
#pragma unroll
        for (int r = 0; r < 4; r++) {
            int i = i0 + quad * 4 + r;
            av[((size_t)i * 8 + b) * 1024 + n * 64 + dt * 16 + lq] = f2bf(o[dt][r] * linv[r]);
        }
}

// ---------------- coverage2: cov[b][j][i] = mean_n prob[b,n,i,j] ----------------
__global__ __launch_bounds__(256) void coverage2(const unsigned short* __restrict__ heads,
                                                 const float* __restrict__ mBuf,
                                                 const float* __restrict__ lBuf,
                                                 float* __restrict__ cov) {
    __shared__ float red[4][16][17];
    const int jc = blockIdx.x, it = blockIdx.y, b = blockIdx.z;
    const int tid = threadIdx.x, wave = tid >> 6, lane = tid & 63;
    const int quad = lane >> 4, lq = lane & 15;
    const int i0 = it * 16;

    v8bf q0[4], q1[4];
    float mr[4][4], li[4][4];
#pragma unroll
    for (int h = 0; h < 4; h++) {
        int n = wave * 4 + h;
        size_t qbase = ((size_t)(i0 + lq) * 8 + b) * AT_HS + n * 64 + quad * 8;
        q0[h] = *(const v8bf*)(heads + qbase);
        q1[h] = *(const v8bf*)(heads + qbase + 32);
        int bn = b * 16 + n;
#pragma unroll
        for (int r = 0; r < 4; r++) {
            int i = i0 + quad * 4 + r;
            mr[h][r] = mBuf[(size_t)bn * AT_T + i];
            li[h][r] = __builtin_amdgcn_rcpf(lBuf[(size_t)bn * AT_T + i]);
        }
    }

    for (int jt = jc * 8; jt < jc * 8 + 8; jt++) {
        const int j0 = jt * 16;
        if (jt <= it) {
            v4f psum = (v4f){0.f, 0.f, 0.f, 0.f};
#pragma unroll
            for (int h = 0; h < 4; h++) {
                int n = wave * 4 + h;
                size_t kbase = ((size_t)(j0 + lq) * 8 + b) * AT_HS + 1024 + n * 64 + quad * 8;
                v8bf k0 = *(const v8bf*)(heads + kbase);
                v8bf k1 = *(const v8bf*)(heads + kbase + 32);
                v4f s = (v4f){0.f, 0.f, 0.f, 0.f};
                s = MFMA16x16x32(q0[h], k0, s);
                s = MFMA16x16x32(q1[h], k1, s);
                int j = j0 + lq;
#pragma unroll
                for (int r = 0; r < 4; r++) {
                    int i = i0 + quad * 4 + r;
                    if (j <= i)
                        psum[r] += exp2f(s[r] * AT_ALPHA - mr[h][r]) * li[h][r];
                }
            }
            __syncthreads();
#pragma unroll
            for (int r = 0; r < 4; r++) red[wave][quad * 4 + r][lq] = psum[r];
            __syncthreads();
            int jl = quad * 4 + wave;
            float v = (red[0][lq][jl] + red[1][lq][jl] + red[2][lq][jl] + red[3][lq][jl]) * 0.0625f;
            cov[(size_t)b * 1048576 + (size_t)(j0 + jl) * 1024 + i0 + lq] = v;
        } else {
            int jl = tid >> 4, il = tid & 15;
            cov[(size_t)b * 1048576 + (size_t)(j0 + jl) * 1024 + i0 + il] = 0.f;
        }
    }
}

// ---------------- launch ----------------
extern "C" void kernel_launch(void* const* d_in, const int* in_sizes, int n_in,
                              void* d_out, int out_size, void* d_ws, size_t ws_size,
                              hipStream_t stream) {
    const float* input = (const float*)d_in[0];
    const float* pos   = (const float*)d_in[1];
    // d_in[2] = attn_mask (deterministic causal; ignored)
    const float* Wqkv  = (const float*)d_in[3];
    const float* Wo    = (const float*)d_in[4];
    float* out = (float*)d_out;

    // workspace layout (bytes)
    char* ws = (char*)d_ws;
    if (ws_size < 93323264) return;  // need ~89 MB
    unsigned short* x     = (unsigned short*)(ws);               // 16,777,216 B (reused as vt)
    unsigned short* heads = (unsigned short*)(ws + 16777216);    // 50,331,648 B
    unsigned short* av    = (unsigned short*)(ws + 67108864);    // 16,777,216 B
    unsigned short* WqkvT = (unsigned short*)(ws + 83886080);    //  6,291,456 B
    unsigned short* WoT   = (unsigned short*)(ws + 90177536);    //  2,097,152 B
    float* mBuf = (float*)(ws + 92274688);                       //    524,288 B
    float* lBuf = (float*)(ws + 92798976);                       //    524,288 B
    unsigned short* vt = x;  // x is dead after the QKV GEMM; vt = [128][64][1024] bf16

    prep_x<<<4096, 256, 0, stream>>>(input, pos, x);
    transpose_f32_bf16<<<dim3(48, 16), 256, 0, stream>>>(Wqkv, WqkvT, 1024, 3072);
    transpose_f32_bf16<<<dim3(16, 16), 256, 0, stream>>>(Wo, WoT, 1024, 1024);
    gemm_bf16<false><<<dim3(24, 64), 256, 0, stream>>>(x, WqkvT, heads, 8192, 3072, 1024);
    transpose_v<<<dim3(16, 16, 8), 256, 0, stream>>>(heads, vt);
    attn_fused2<<<dim3(64, 32), 256, 0, stream>>>(heads, vt, av, mBuf, lBuf);
    coverage2<<<dim3(8, 64, 8), 256, 0, stream>>>(heads, mBuf, lBuf, out + 8388608);
    gemm_bf16<true><<<dim3(8, 64), 256, 0, stream>>>(av, WoT, out, 8192, 1024, 1024);
}

// Round 7
// 544.966 us; speedup vs baseline: 1.1058x; 1.1058x over previous
//
#include <hip/hip_runtime.h>
#include <hip/hip_bf16.h>

// Problem constants: T=1024, B=8, D=1024, N_HEAD=16, D_HEAD=64
// I/O dtype: fp32 (per reference). Internal compute: bf16 MFMA with fp32 accum.
// heads buffer layout: [T*B][3072] bf16, cols [0,1024)=Q, [1024,2048)=K, [2048,3072)=V

typedef __bf16 v8bf __attribute__((ext_vector_type(8)));
typedef float  v4f  __attribute__((ext_vector_type(4)));
typedef unsigned short v8us __attribute__((ext_vector_type(8)));

#define MFMA16x16x32(a, b, c) __builtin_amdgcn_mfma_f32_16x16x32_bf16(a, b, c, 0, 0, 0)

__device__ __forceinline__ unsigned short f2bf(float f) {
    unsigned int u = __float_as_uint(f);
    u = (u + 0x7FFF + ((u >> 16) & 1)) >> 16;   // RNE
    return (unsigned short)u;
}

// ---------------- prep: x_bf16 = bf16(input_f32 + pos_enc_f32) ----------------
__global__ __launch_bounds__(256) void prep_x(const float* __restrict__ in,
                                              const float* __restrict__ pe,
                                              unsigned short* __restrict__ x) {
    size_t idx = ((size_t)blockIdx.x * 256 + threadIdx.x) * 8;
    v4f a0 = *(const v4f*)(in + idx);
    v4f a1 = *(const v4f*)(in + idx + 4);
    v4f p0 = *(const v4f*)(pe + idx);
    v4f p1 = *(const v4f*)(pe + idx + 4);
    v8us r;
    unsigned short* rp = (unsigned short*)&r;
#pragma unroll
    for (int q = 0; q < 4; q++) {
        rp[q]     = f2bf(a0[q] + p0[q]);
        rp[q + 4] = f2bf(a1[q] + p1[q]);
    }
    *(v8us*)(x + idx) = r;
}

// -------- tiled transpose + cast: src_f32[R][C] -> dst_bf16[C][R] ----------
__global__ __launch_bounds__(256) void transpose_f32_bf16(const float* __restrict__ src,
                                                          unsigned short* __restrict__ dst,
                                                          int R, int C) {
    __shared__ alignas(16) unsigned short t[64][72];
    int c0 = blockIdx.x * 64, r0 = blockIdx.y * 64;
    int tid = threadIdx.x;
    int rr = tid >> 2, cg = (tid & 3) * 16;
    const float* s = src + (size_t)(r0 + rr) * C + c0 + cg;
#pragma unroll
    for (int q4 = 0; q4 < 4; q4++) {
        v4f v = *(const v4f*)(s + q4 * 4);
#pragma unroll
        for (int q = 0; q < 4; q++) t[rr][cg + q4 * 4 + q] = f2bf(v[q]);
    }
    __syncthreads();
    v8us o0, o1;
    unsigned short* o0p = (unsigned short*)&o0;
    unsigned short* o1p = (unsigned short*)&o1;
#pragma unroll
    for (int q = 0; q < 8; q++) {
        o0p[q] = t[cg + q][rr];
        o1p[q] = t[cg + 8 + q][rr];
    }
    *(v8us*)(dst + (size_t)(c0 + rr) * R + r0 + cg)     = o0;
    *(v8us*)(dst + (size_t)(c0 + rr) * R + r0 + cg + 8) = o1;
}

// ---------------- GEMM: C[M][N] = A[M][K] * Bt[N][K]^T, bf16 in, fp32 acc --------
template <bool F32OUT>
__global__ __launch_bounds__(256) void gemm_bf16(const unsigned short* __restrict__ A,
                                                 const unsigned short* __restrict__ Bt,
                                                 void* __restrict__ Cout,
                                                 int M, int N, int K) {
    __shared__ alignas(16) unsigned short As[128][40];
    __shared__ alignas(16) unsigned short Bs[128][40];
    const int tid = threadIdx.x;
    const int lane = tid & 63, wave = tid >> 6;
    const int quad = lane >> 4, lq = lane & 15;
    const int m0 = blockIdx.y * 128, n0 = blockIdx.x * 128;
    const int mW = (wave & 1) * 64, nW = (wave >> 1) * 64;

    v4f acc[4][4];
#pragma unroll
    for (int mi = 0; mi < 4; mi++)
#pragma unroll
        for (int ni = 0; ni < 4; ni++) acc[mi][ni] = (v4f){0.f, 0.f, 0.f, 0.f};

    const int srow = tid >> 1, shalf = (tid & 1) * 16;
    const unsigned short* ag = A  + (size_t)(m0 + srow) * K + shalf;
    const unsigned short* bg = Bt + (size_t)(n0 + srow) * K + shalf;

    for (int k0 = 0; k0 < K; k0 += 32) {
        v8us a0 = *(const v8us*)(ag + k0);
        v8us a1 = *(const v8us*)(ag + k0 + 8);
        v8us b0 = *(const v8us*)(bg + k0);
        v8us b1 = *(const v8us*)(bg + k0 + 8);
        __syncthreads();
        *(v8us*)&As[srow][shalf]     = a0;
        *(v8us*)&As[srow][shalf + 8] = a1;
        *(v8us*)&Bs[srow][shalf]     = b0;
        *(v8us*)&Bs[srow][shalf + 8] = b1;
        __syncthreads();
        v8bf af[4], bfr[4];
#pragma unroll
        for (int mi = 0; mi < 4; mi++) af[mi]  = *(const v8bf*)&As[mW + mi * 16 + lq][quad * 8];
#pragma unroll
        for (int ni = 0; ni < 4; ni++) bfr[ni] = *(const v8bf*)&Bs[nW + ni * 16 + lq][quad * 8];
#pragma unroll
        for (int mi = 0; mi < 4; mi++)
#pragma unroll
            for (int ni = 0; ni < 4; ni++)
                acc[mi][ni] = MFMA16x16x32(af[mi], bfr[ni], acc[mi][ni]);
    }

#pragma unroll
    for (int mi = 0; mi < 4; mi++)
#pragma unroll
        for (int ni = 0; ni < 4; ni++)
#pragma unroll
            for (int r = 0; r < 4; r++) {
                int row = m0 + mW + mi * 16 + quad * 4 + r;
                int col = n0 + nW + ni * 16 + lq;
                if (F32OUT)
                    ((float*)Cout)[(size_t)row * N + col] = acc[mi][ni][r];
                else
                    ((unsigned short*)Cout)[(size_t)row * N + col] = f2bf(acc[mi][ni][r]);
            }
}

// ---------------- attention constants ----------------
#define AT_T  1024
#define AT_B  8
#define AT_NH 16
#define AT_HS 3072
#define AT_ALPHA 0.18033688011112042f  // (1/8) * log2(e)

// ---------------- attn_fused3: one wave per (b, n, 16-row i-tile) ----------------
// Pass 1: row MAX only (no exp2) — MFMA + fmax, one 4-step shfl reduce at end.
// Pass 2: fixed-M sum + PV accumulate; P unnormalized (normalize in epilogue).
// K and V read directly from heads (proven L2-friendly); P via wave-private LDS.
__global__ __launch_bounds__(64) void attn_fused3(const unsigned short* __restrict__ heads,
                                                  unsigned short* __restrict__ av,
                                                  float* __restrict__ mBuf,
                                                  float* __restrict__ lBuf) {
    __shared__ alignas(16) unsigned short Ps[16][40];
    const int bn = blockIdx.x, b = bn >> 4, n = bn & 15;
    const int lane = threadIdx.x, quad = lane >> 4, lq = lane & 15;
    const int i0 = blockIdx.y * 16;

    size_t qbase = ((size_t)(i0 + lq) * 8 + b) * AT_HS + n * 64 + quad * 8;
    v8bf q0 = *(const v8bf*)(heads + qbase);
    v8bf q1 = *(const v8bf*)(heads + qbase + 32);

    // ---- pass 1: per-row max only ----
    float M[4];
#pragma unroll
    for (int r = 0; r < 4; r++) M[r] = -1e30f;

    for (int j0 = 0; j0 <= i0; j0 += 16) {
        size_t kbase = ((size_t)(j0 + lq) * 8 + b) * AT_HS + 1024 + n * 64 + quad * 8;
        v8bf k0 = *(const v8bf*)(heads + kbase);
        v8bf k1 = *(const v8bf*)(heads + kbase + 32);
        v4f s = (v4f){0.f, 0.f, 0.f, 0.f};
        s = MFMA16x16x32(q0, k0, s);
        s = MFMA16x16x32(q1, k1, s);
        int j = j0 + lq;
#pragma unroll
        for (int r = 0; r < 4; r++) {
            int i = i0 + quad * 4 + r;
            if (j <= i) M[r] = fmaxf(M[r], s[r] * AT_ALPHA);
        }
    }
#pragma unroll
    for (int mask = 1; mask < 16; mask <<= 1)
#pragma unroll
        for (int r = 0; r < 4; r++)
            M[r] = fmaxf(M[r], __shfl_xor(M[r], mask));

    // ---- pass 2: sum + O accumulate with fixed M ----
    float Sl[4];
    v4f o[4];
#pragma unroll
    for (int r = 0; r < 4; r++) Sl[r] = 0.f;
#pragma unroll
    for (int dt = 0; dt < 4; dt++) o[dt] = (v4f){0.f, 0.f, 0.f, 0.f};

    for (int j0 = 0; j0 < i0 + 16; j0 += 32) {
        v4f s0 = (v4f){0.f, 0.f, 0.f, 0.f}, s1 = s0;
        {
            size_t kb0 = ((size_t)(j0 + lq) * 8 + b) * AT_HS + 1024 + n * 64 + quad * 8;
            size_t kb1 = ((size_t)(j0 + 16 + lq) * 8 + b) * AT_HS + 1024 + n * 64 + quad * 8;
            v8bf ka = *(const v8bf*)(heads + kb0);
            v8bf kb = *(const v8bf*)(heads + kb0 + 32);
            v8bf kc = *(const v8bf*)(heads + kb1);
            v8bf kd = *(const v8bf*)(heads + kb1 + 32);
            s0 = MFMA16x16x32(q0, ka, s0);
            s0 = MFMA16x16x32(q1, kb, s0);
            s1 = MFMA16x16x32(q0, kc, s1);
            s1 = MFMA16x16x32(q1, kd, s1);
        }
        int ja = j0 + lq, jb_ = j0 + 16 + lq;
#pragma unroll
        for (int r = 0; r < 4; r++) {
            int i = i0 + quad * 4 + r;
            float v0 = (ja  <= i) ? s0[r] * AT_ALPHA : -1e30f;
            float v1 = (jb_ <= i) ? s1[r] * AT_ALPHA : -1e30f;
            float p0 = exp2f(v0 - M[r]);   // masked lanes -> 0
            float p1 = exp2f(v1 - M[r]);
            Sl[r] += p0 + p1;
            Ps[quad * 4 + r][lq]      = f2bf(p0);
            Ps[quad * 4 + r][16 + lq] = f2bf(p1);
        }
        __syncthreads();
        v8bf pf = *(const v8bf*)&Ps[lq][quad * 8];
#pragma unroll
        for (int dt = 0; dt < 4; dt++) {
            v8bf vf;
            unsigned short* vp = (unsigned short*)&vf;
#pragma unroll
            for (int jj = 0; jj < 8; jj++) {
                int j = j0 + quad * 8 + jj;
                vp[jj] = heads[((size_t)j * 8 + b) * AT_HS + 2048 + n * 64 + dt * 16 + lq];
            }
            o[dt] = MFMA16x16x32(pf, vf, o[dt]);
        }
        __syncthreads();   // Ps reused next chunk
    }

    // reduce per-lane partial sums across the 16 lanes of each row
#pragma unroll
    for (int mask = 1; mask < 16; mask <<= 1)
#pragma unroll
        for (int r = 0; r < 4; r++)
            Sl[r] += __shfl_xor(Sl[r], mask);
    float linv[4];
#pragma unroll
    for (int r = 0; r < 4; r++) linv[r] = __builtin_amdgcn_rcpf(Sl[r]);
    if (lq == 0) {
#pragma unroll
        for (int r = 0; r < 4; r++) {
            int i = i0 + quad * 4 + r;
            mBuf[(size_t)bn * AT_T + i] = M[r];
            lBuf[(size_t)bn * AT_T + i] = Sl[r];
        }
    }
#pragma unroll
    for (int dt = 0; dt < 4; dt++)
#pragma unroll
        for (int r = 0; r < 4; r++) {
            int i = i0 + quad * 4 + r;
            av[((size_t)i * 8 + b) * 1024 + n * 64 + dt * 16 + lq] = f2bf(o[dt][r] * linv[r]);
        }
}

// ---------------- coverage2: cov[b][j][i] = mean_n prob[b,n,i,j] ----------------
__global__ __launch_bounds__(256) void coverage2(const unsigned short* __restrict__ heads,
                                                 const float* __restrict__ mBuf,
                                                 const float* __restrict__ lBuf,
                                                 float* __restrict__ cov) {
    __shared__ float red[4][16][17];
    const int jc = blockIdx.x, it = blockIdx.y, b = blockIdx.z;
    const int tid = threadIdx.x, wave = tid >> 6, lane = tid & 63;
    const int quad = lane >> 4, lq = lane & 15;
    const int i0 = it * 16;

    v8bf q0[4], q1[4];
    float mr[4][4], li[4][4];
#pragma unroll
    for (int h = 0; h < 4; h++) {
        int n = wave * 4 + h;
        size_t qbase = ((size_t)(i0 + lq) * 8 + b) * AT_HS + n * 64 + quad * 8;
        q0[h] = *(const v8bf*)(heads + qbase);
        q1[h] = *(const v8bf*)(heads + qbase + 32);
        int bn = b * 16 + n;
#pragma unroll
        for (int r = 0; r < 4; r++) {
            int i = i0 + quad * 4 + r;
            mr[h][r] = mBuf[(size_t)bn * AT_T + i];
            li[h][r] = __builtin_amdgcn_rcpf(lBuf[(size_t)bn * AT_T + i]);
        }
    }

    for (int jt = jc * 8; jt < jc * 8 + 8; jt++) {
        const int j0 = jt * 16;
        if (jt <= it) {
            v4f psum = (v4f){0.f, 0.f, 0.f, 0.f};
#pragma unroll
            for (int h = 0; h < 4; h++) {
                int n = wave * 4 + h;
                size_t kbase = ((size_t)(j0 + lq) * 8 + b) * AT_HS + 1024 + n * 64 + quad * 8;
                v8bf k0 = *(const v8bf*)(heads + kbase);
                v8bf k1 = *(const v8bf*)(heads + kbase + 32);
                v4f s = (v4f){0.f, 0.f, 0.f, 0.f};
                s = MFMA16x16x32(q0[h], k0, s);
                s = MFMA16x16x32(q1[h], k1, s);
                int j = j0 + lq;
#pragma unroll
                for (int r = 0; r < 4; r++) {
                    int i = i0 + quad * 4 + r;
                    if (j <= i)
                        psum[r] += exp2f(s[r] * AT_ALPHA - mr[h][r]) * li[h][r];
                }
            }
            __syncthreads();
#pragma unroll
            for (int r = 0; r < 4; r++) red[wave][quad * 4 + r][lq] = psum[r];
            __syncthreads();
            int jl = quad * 4 + wave;
            float v = (red[0][lq][jl] + red[1][lq][jl] + red[2][lq][jl] + red[3][lq][jl]) * 0.0625f;
            cov[(size_t)b * 1048576 + (size_t)(j0 + jl) * 1024 + i0 + lq] = v;
        } else {
            int jl = tid >> 4, il = tid & 15;
            cov[(size_t)b * 1048576 + (size_t)(j0 + jl) * 1024 + i0 + il] = 0.f;
        }
    }
}

// ---------------- launch ----------------
extern "C" void kernel_launch(void* const* d_in, const int* in_sizes, int n_in,
                              void* d_out, int out_size, void* d_ws, size_t ws_size,
                              hipStream_t stream) {
    const float* input = (const float*)d_in[0];
    const float* pos   = (const float*)d_in[1];
    // d_in[2] = attn_mask (deterministic causal; ignored)
    const float* Wqkv  = (const float*)d_in[3];
    const float* Wo    = (const float*)d_in[4];
    float* out = (float*)d_out;

    // workspace layout (bytes)
    char* ws = (char*)d_ws;
    if (ws_size < 93323264) return;  // need ~89 MB
    unsigned short* x     = (unsigned short*)(ws);               // 16,777,216 B
    unsigned short* heads = (unsigned short*)(ws + 16777216);    // 50,331,648 B
    unsigned short* av    = (unsigned short*)(ws + 67108864);    // 16,777,216 B
    unsigned short* WqkvT = (unsigned short*)(ws + 83886080);    //  6,291,456 B
    unsigned short* WoT   = (unsigned short*)(ws + 90177536);    //  2,097,152 B
    float* mBuf = (float*)(ws + 92274688);                       //    524,288 B
    float* lBuf = (float*)(ws + 92798976);                       //    524,288 B

    prep_x<<<4096, 256, 0, stream>>>(input, pos, x);
    transpose_f32_bf16<<<dim3(48, 16), 256, 0, stream>>>(Wqkv, WqkvT, 1024, 3072);
    transpose_f32_bf16<<<dim3(16, 16), 256, 0, stream>>>(Wo, WoT, 1024, 1024);
    gemm_bf16<false><<<dim3(24, 64), 256, 0, stream>>>(x, WqkvT, heads, 8192, 3072, 1024);
    attn_fused3<<<dim3(128, 64), 64, 0, stream>>>(heads, av, mBuf, lBuf);
    coverage2<<<dim3(8, 64, 8), 256, 0, stream>>>(heads, mBuf, lBuf, out + 8388608);
    gemm_bf16<true><<<dim3(8, 64), 256, 0, stream>>>(av, WoT, out, 8192, 1024, 1024);
}